// Round 1
// baseline (563.682 us; speedup 1.0000x reference)
//
#include <hip/hip_runtime.h>
#include <hip/hip_bf16.h>

// Problem constants (from reference)
constexpr int kNFine   = 1000000;
constexpr int kNCoarse = 250000;
constexpr int kValDim  = 32;
constexpr int kFExt    = 9;      // filter extent (K blocks of 32)
constexpr int kNrF     = 64;     // output filters
constexpr int kPackedElems = kFExt * 4 * 64 * 8; // 18432 bf16 = 36 KB

typedef __attribute__((ext_vector_type(8))) short bf16x8;
typedef __attribute__((ext_vector_type(4))) float floatx4;

__device__ inline short f2bf(float x) {
    __hip_bfloat16 h = __float2bfloat16(x);
    short s;
    __builtin_memcpy(&s, &h, sizeof(short));
    return s;
}

// Pack weight [288][64] fp32 -> bf16 in MFMA B-fragment order:
// chunk c = (kb*4 + nt)*64 + lane, element jj (0..7):
//   value = W[kb*32 + (lane>>4)*8 + jj][nt*16 + (lane&15)]
// Thread t maps to OUTPUT element t -> coalesced writes, L2-hot scattered reads.
__global__ void pack_weight_kernel(const float* __restrict__ w, short* __restrict__ wp) {
    int t = blockIdx.x * blockDim.x + threadIdx.x;
    if (t >= kPackedElems) return;
    int jj   = t & 7;
    int lane = (t >> 3) & 63;
    int nt   = (t >> 9) & 3;
    int kb   = t >> 11;
    int k = kb * 32 + (lane >> 4) * 8 + jj;
    int n = nt * 16 + (lane & 15);
    wp[t] = f2bf(w[k * kNrF + n]);
}

// Each wave: M=32 vertices (2 sub-tiles of 16), N=64 (4 n-tiles of 16), K=288 (9 kb steps).
// Block = 4 waves = 128 vertices per tile; grid-stride over tiles.
__global__ __launch_bounds__(256, 4)
void finefy_kernel(const float* __restrict__ cv, const int* __restrict__ nbr,
                   const short* __restrict__ wp, float* __restrict__ out, int ntiles) {
    __shared__ __align__(16) short wlds[kPackedElems]; // 36 KB

    // Stage packed weight into LDS (coalesced 16B copies)
    for (int i = threadIdx.x; i < kPackedElems / 8; i += 256) {
        ((int4*)wlds)[i] = ((const int4*)wp)[i];
    }
    __syncthreads();

    const int wave = threadIdx.x >> 6;
    const int lane = threadIdx.x & 63;
    const int quad = lane >> 4;
    const int lm   = lane & 15;

    const floatx4 vzero = {0.f, 0.f, 0.f, 0.f};

    for (int tile = blockIdx.x; tile < ntiles; tile += gridDim.x) {
        const int vb = tile * 128 + wave * 32;
        // Vertex for A-fragment rows of each sub-tile (clamped for the tail tile;
        // stores are guarded, so clamped loads only affect dead lanes).
        const int v0 = min(vb + lm,      kNFine - 1);
        const int v1 = min(vb + 16 + lm, kNFine - 1);

        int idx0[kFExt], idx1[kFExt];
#pragma unroll
        for (int j = 0; j < kFExt; ++j) idx0[j] = nbr[v0 * kFExt + j];
#pragma unroll
        for (int j = 0; j < kFExt; ++j) idx1[j] = nbr[v1 * kFExt + j];

        floatx4 acc[2][4];
#pragma unroll
        for (int s = 0; s < 2; ++s)
#pragma unroll
            for (int nt = 0; nt < 4; ++nt) acc[s][nt] = vzero;

#pragma unroll
        for (int kb = 0; kb < kFExt; ++kb) {
            // A fragment: lane L holds A[m=lm][k=quad*8+jj] = coarse[idx[m][kb]][quad*8+jj]
            const float* p0 = cv + (size_t)idx0[kb] * kValDim + quad * 8;
            const float* p1 = cv + (size_t)idx1[kb] * kValDim + quad * 8;
            floatx4 a0lo = *(const floatx4*)p0;
            floatx4 a0hi = *(const floatx4*)(p0 + 4);
            floatx4 a1lo = *(const floatx4*)p1;
            floatx4 a1hi = *(const floatx4*)(p1 + 4);
            bf16x8 a0, a1;
#pragma unroll
            for (int e = 0; e < 4; ++e) {
                a0[e]     = f2bf(a0lo[e]);
                a0[e + 4] = f2bf(a0hi[e]);
                a1[e]     = f2bf(a1lo[e]);
                a1[e + 4] = f2bf(a1hi[e]);
            }
#pragma unroll
            for (int nt = 0; nt < 4; ++nt) {
                bf16x8 b = *(const bf16x8*)&wlds[((kb * 4 + nt) * 64 + lane) * 8];
                acc[0][nt] = __builtin_amdgcn_mfma_f32_16x16x32_bf16(a0, b, acc[0][nt], 0, 0, 0);
                acc[1][nt] = __builtin_amdgcn_mfma_f32_16x16x32_bf16(a1, b, acc[1][nt], 0, 0, 0);
            }
        }

        // Store: D[row=quad*4+r][col=lm]; out[v][nt*16 + lm]
#pragma unroll
        for (int s = 0; s < 2; ++s) {
            const int rbase = vb + s * 16 + quad * 4;
#pragma unroll
            for (int r = 0; r < 4; ++r) {
                const int v = rbase + r;
                if (v < kNFine) {
                    float* o = out + (size_t)v * kNrF + lm;
                    o[0]  = acc[s][0][r];
                    o[16] = acc[s][1][r];
                    o[32] = acc[s][2][r];
                    o[48] = acc[s][3][r];
                }
            }
        }
    }
}

extern "C" void kernel_launch(void* const* d_in, const int* in_sizes, int n_in,
                              void* d_out, int out_size, void* d_ws, size_t ws_size,
                              hipStream_t stream) {
    const float* cv  = (const float*)d_in[0];  // coarse_values [250000, 32]
    const int*   nbr = (const int*)d_in[1];    // neighbor_indices [1000000, 9]
    const float* w   = (const float*)d_in[2];  // weight [288, 64]
    float* out = (float*)d_out;                // [1000000, 64]
    short* wp  = (short*)d_ws;                 // 36 KB packed bf16 weight

    pack_weight_kernel<<<(kPackedElems + 255) / 256, 256, 0, stream>>>(w, wp);

    const int ntiles = (kNFine + 127) / 128;   // 7813
    finefy_kernel<<<1024, 256, 0, stream>>>(cv, nbr, wp, out, ntiles);
}

// Round 2
// 449.370 us; speedup vs baseline: 1.2544x; 1.2544x over previous
//
#include <hip/hip_runtime.h>
#include <hip/hip_bf16.h>

// Problem constants (from reference)
constexpr int kNFine   = 1000000;
constexpr int kNCoarse = 250000;
constexpr int kValDim  = 32;
constexpr int kFExt    = 9;      // filter extent (K blocks of 32)
constexpr int kNrF     = 64;     // output filters
constexpr int kPackedElems = kFExt * 4 * 64 * 8;       // 18432 bf16 = 36 KB
constexpr int kCoarseElems = kNCoarse * kValDim;       // 8,000,000

typedef __attribute__((ext_vector_type(8))) short bf16x8;
typedef __attribute__((ext_vector_type(4))) float floatx4;

__device__ inline short f2bf(float x) {
    __hip_bfloat16 h = __float2bfloat16(x);
    short s;
    __builtin_memcpy(&s, &h, sizeof(short));
    return s;
}

// Pack weight [288][64] fp32 -> bf16 in MFMA B-fragment order:
// chunk c = (kb*4 + nt)*64 + lane, element jj (0..7):
//   value = W[kb*32 + (lane>>4)*8 + jj][nt*16 + (lane&15)]
__global__ void pack_weight_kernel(const float* __restrict__ w, short* __restrict__ wp) {
    int t = blockIdx.x * blockDim.x + threadIdx.x;
    if (t >= kPackedElems) return;
    int jj   = t & 7;
    int lane = (t >> 3) & 63;
    int nt   = (t >> 9) & 3;
    int kb   = t >> 11;
    int k = kb * 32 + (lane >> 4) * 8 + jj;
    int n = nt * 16 + (lane & 15);
    wp[t] = f2bf(w[k * kNrF + n]);
}

// Convert coarse_values [250000,32] fp32 -> bf16 (halves gather bytes,
// removes per-gather cvt VALU work from the hot kernel).
__global__ __launch_bounds__(256)
void convert_coarse_kernel(const float* __restrict__ cv, short* __restrict__ cb) {
    int t = blockIdx.x * blockDim.x + threadIdx.x;   // one thread per 8 elements
    if (t >= kCoarseElems / 8) return;
    floatx4 lo = ((const floatx4*)cv)[t * 2];
    floatx4 hi = ((const floatx4*)cv)[t * 2 + 1];
    bf16x8 o;
#pragma unroll
    for (int e = 0; e < 4; ++e) {
        o[e]     = f2bf(lo[e]);
        o[e + 4] = f2bf(hi[e]);
    }
    ((bf16x8*)cb)[t] = o;
}

// Each wave: M=32 vertices (2 sub-tiles of 16), N=64 (4 n-tiles of 16), K=288.
// Block = 8 waves = 256 vertices per tile, one tile per block.
// LDS 36 KB -> 4 blocks/CU; 512 threads -> 32 waves/CU (100% occupancy cap).
__global__ __launch_bounds__(512, 8)
void finefy_kernel(const short* __restrict__ cb, const int* __restrict__ nbr,
                   const short* __restrict__ wp, float* __restrict__ out) {
    __shared__ __align__(16) short wlds[kPackedElems]; // 36 KB

    for (int i = threadIdx.x; i < kPackedElems / 8; i += 512) {
        ((int4*)wlds)[i] = ((const int4*)wp)[i];
    }
    __syncthreads();

    const int wave = threadIdx.x >> 6;
    const int lane = threadIdx.x & 63;
    const int quad = lane >> 4;
    const int lm   = lane & 15;

    const int vb = blockIdx.x * 256 + wave * 32;
    // Clamp for the tail tile; stores are guarded so clamped loads only feed dead lanes.
    const int v0 = min(vb + lm,      kNFine - 1);
    const int v1 = min(vb + 16 + lm, kNFine - 1);

    int idx0[kFExt], idx1[kFExt];
#pragma unroll
    for (int j = 0; j < kFExt; ++j) idx0[j] = nbr[v0 * kFExt + j];
#pragma unroll
    for (int j = 0; j < kFExt; ++j) idx1[j] = nbr[v1 * kFExt + j];

    const floatx4 vzero = {0.f, 0.f, 0.f, 0.f};
    floatx4 acc[2][4];
#pragma unroll
    for (int s = 0; s < 2; ++s)
#pragma unroll
        for (int nt = 0; nt < 4; ++nt) acc[s][nt] = vzero;

#pragma unroll
    for (int kb = 0; kb < kFExt; ++kb) {
        // A fragment: lane L holds A[m=lm][k=quad*8+jj] = coarse_bf16[idx[m][kb]][quad*8+jj]
        // One 16 B load per sub-tile per kb (row is 64 B, 16 B-aligned slices).
        bf16x8 a0 = *(const bf16x8*)(cb + (size_t)idx0[kb] * kValDim + quad * 8);
        bf16x8 a1 = *(const bf16x8*)(cb + (size_t)idx1[kb] * kValDim + quad * 8);
#pragma unroll
        for (int nt = 0; nt < 4; ++nt) {
            bf16x8 b = *(const bf16x8*)&wlds[((kb * 4 + nt) * 64 + lane) * 8];
            acc[0][nt] = __builtin_amdgcn_mfma_f32_16x16x32_bf16(a0, b, acc[0][nt], 0, 0, 0);
            acc[1][nt] = __builtin_amdgcn_mfma_f32_16x16x32_bf16(a1, b, acc[1][nt], 0, 0, 0);
        }
    }

    // Store: D[row=quad*4+r][col=lm]; out[v][nt*16 + lm]. Non-temporal to keep
    // the 256 MB output stream from evicting the coarse table out of L2.
#pragma unroll
    for (int s = 0; s < 2; ++s) {
        const int rbase = vb + s * 16 + quad * 4;
#pragma unroll
        for (int r = 0; r < 4; ++r) {
            const int v = rbase + r;
            if (v < kNFine) {
                float* o = out + (size_t)v * kNrF + lm;
                __builtin_nontemporal_store(acc[s][0][r], o);
                __builtin_nontemporal_store(acc[s][1][r], o + 16);
                __builtin_nontemporal_store(acc[s][2][r], o + 32);
                __builtin_nontemporal_store(acc[s][3][r], o + 48);
            }
        }
    }
}

extern "C" void kernel_launch(void* const* d_in, const int* in_sizes, int n_in,
                              void* d_out, int out_size, void* d_ws, size_t ws_size,
                              hipStream_t stream) {
    const float* cv  = (const float*)d_in[0];  // coarse_values [250000, 32]
    const int*   nbr = (const int*)d_in[1];    // neighbor_indices [1000000, 9]
    const float* w   = (const float*)d_in[2];  // weight [288, 64]
    float* out = (float*)d_out;                // [1000000, 64]

    // Workspace layout: [0, 64KB) packed weight; [64KB, 64KB+16MB) bf16 coarse.
    short* wp = (short*)d_ws;
    short* cb = (short*)((char*)d_ws + 65536);

    pack_weight_kernel<<<(kPackedElems + 255) / 256, 256, 0, stream>>>(w, wp);
    convert_coarse_kernel<<<(kCoarseElems / 8 + 255) / 256, 256, 0, stream>>>(cv, cb);

    const int ntiles = (kNFine + 255) / 256;   // 3907 blocks, one tile each
    finefy_kernel<<<ntiles, 512, 0, stream>>>(cb, nbr, wp, out);
}